// Round 3
// baseline (178.751 us; speedup 1.0000x reference)
//
#include <hip/hip_runtime.h>

// DeLaN sin-net fused kernel for MI355X (gfx950).
//
// R2: split each path into (a) transcendental burst -> s[30],c[30] registers,
// (b) uninterrupted 30x60 FMA matvec with weights streamed via scalar loads
// from a linear per-h packed layout ([h][64] = PT row | AT row). Removes the
// s_load->wait->sin->fma serialization that held VALUBusy at 43%.

#define NT 256

// ---- packed weight layout in d_ws (floats) ----
constexpr int OFF_LD   = 0;     // [h][64]: {PT[h][j] j<30,pad2, AT[h][j] j<30,pad2}
constexpr int OFF_LO   = 1920;  // [h][64]: {QT[h][j] j<30,pad2, BT[h][j] j<30,pad2}
constexpr int OFF_W1LD = 3840;  // [h][8], d<7  : ld_w1
constexpr int OFF_W1LO = 4080;  // [h][8]       : lo_w1
constexpr int OFF_W1G  = 4320;  // [h][8]       : g_w1
constexpr int OFF_G2T  = 4560;  // [h][8], k<7  : g_w2^T
constexpr int OFF_M2T  = 4800;  // [j][8], k<7  : m_w2^T
constexpr int OFF_C2T  = 5040;  // [j][8], k<7  : c_w2^T
constexpr int OFF_MQT  = 5280;  // [d][32], d<7 : m_w1[:,28+d] (qDDot part)
constexpr int OFF_CQT  = 5504;  // [d][32], d<7 : c_w1[:,196+d] (qDot part)
constexpr int OFF_BLD  = 5728;  // 30 : ld_b1
constexpr int OFF_BLO  = 5758;  // 30 : lo_b1
constexpr int OFF_BG   = 5788;  // 30 : g_b1
constexpr int OFF_BM   = 5818;  // 30 : m_b1 + m_w1[:, :28] @ [ld_b2;lo_b2]
constexpr int OFF_BC   = 5848;  // 30 : c_b1
constexpr int OFF_BOUT = 5878;  // 7  : m_b2 + c_b2 + g_b2
constexpr int WS_N     = 5888;  // 23.5 KB

__global__ void precompute_kernel(
    const float* __restrict__ ld_w1, const float* __restrict__ ld_b1,
    const float* __restrict__ ld_w2, const float* __restrict__ ld_b2,
    const float* __restrict__ lo_w1, const float* __restrict__ lo_b1,
    const float* __restrict__ lo_w2, const float* __restrict__ lo_b2,
    const float* __restrict__ g_w1,  const float* __restrict__ g_b1,
    const float* __restrict__ g_w2,  const float* __restrict__ g_b2,
    const float* __restrict__ m_w1,  const float* __restrict__ m_b1,
    const float* __restrict__ m_w2,  const float* __restrict__ m_b2,
    const float* __restrict__ c_w1,  const float* __restrict__ c_b1,
    const float* __restrict__ c_w2,  const float* __restrict__ c_b2,
    float* __restrict__ ws)
{
    int i = blockIdx.x * blockDim.x + threadIdx.x;
    if (i < 900) {                       // AT[h][j] = sum_{o<7,d} c_w1[j,o*7+d]*ld_w2[o,h]*ld_w1[h,d]
        int h = i / 30, j = i % 30;
        float acc = 0.f;
#pragma unroll
        for (int o = 0; o < 7; ++o) {
            float t = 0.f;
#pragma unroll
            for (int d = 0; d < 7; ++d) t += c_w1[j*203 + o*7 + d] * ld_w1[h*7 + d];
            acc += ld_w2[o*30 + h] * t;
        }
        ws[OFF_LD + h*64 + 32 + j] = acc;
    } else if (i < 1800) {               // BT[h][j] = sum_{o<21,d} c_w1[j,(7+o)*7+d]*lo_w2[o,h]*lo_w1[h,d]
        int e = i - 900, h = e / 30, j = e % 30;
        float acc = 0.f;
#pragma unroll
        for (int o = 0; o < 21; ++o) {
            float t = 0.f;
#pragma unroll
            for (int d = 0; d < 7; ++d) t += c_w1[j*203 + (7+o)*7 + d] * lo_w1[h*7 + d];
            acc += lo_w2[o*30 + h] * t;
        }
        ws[OFF_LO + h*64 + 32 + j] = acc;
    } else if (i < 2700) {               // PT[h][j] = sum_{o<7} m_w1[j,o]*ld_w2[o,h]
        int e = i - 1800, h = e / 30, j = e % 30;
        float acc = 0.f;
#pragma unroll
        for (int o = 0; o < 7; ++o) acc += m_w1[j*35 + o] * ld_w2[o*30 + h];
        ws[OFF_LD + h*64 + j] = acc;
    } else if (i < 3600) {               // QT[h][j] = sum_{o<21} m_w1[j,7+o]*lo_w2[o,h]
        int e = i - 2700, h = e / 30, j = e % 30;
        float acc = 0.f;
#pragma unroll
        for (int o = 0; o < 21; ++o) acc += m_w1[j*35 + 7 + o] * lo_w2[o*30 + h];
        ws[OFF_LO + h*64 + j] = acc;
    } else if (i < 3810) { int e = i - 3600; ws[OFF_W1LD + (e/7)*8 + e%7] = ld_w1[e]; }
    else if (i < 4020) { int e = i - 3810; ws[OFF_W1LO + (e/7)*8 + e%7] = lo_w1[e]; }
    else if (i < 4230) { int e = i - 4020; ws[OFF_W1G  + (e/7)*8 + e%7] = g_w1[e]; }
    else if (i < 4440) { int e = i - 4230; int h = e/7, k = e%7; ws[OFF_G2T + h*8 + k] = g_w2[k*30 + h]; }
    else if (i < 4650) { int e = i - 4440; int j = e/7, k = e%7; ws[OFF_M2T + j*8 + k] = m_w2[k*30 + j]; }
    else if (i < 4860) { int e = i - 4650; int j = e/7, k = e%7; ws[OFF_C2T + j*8 + k] = c_w2[k*30 + j]; }
    else if (i < 5070) { int e = i - 4860; int d = e/30, j = e%30; ws[OFF_MQT + d*32 + j] = m_w1[j*35 + 28 + d]; }
    else if (i < 5280) { int e = i - 5070; int d = e/30, j = e%30; ws[OFF_CQT + d*32 + j] = c_w1[j*203 + 196 + d]; }
    else if (i < 5310) { int j = i - 5280; ws[OFF_BLD + j] = ld_b1[j]; }
    else if (i < 5340) { int j = i - 5310; ws[OFF_BLO + j] = lo_b1[j]; }
    else if (i < 5370) { int j = i - 5340; ws[OFF_BG + j] = g_b1[j]; }
    else if (i < 5400) {                 // BM[j] = m_b1[j] + m_w1[j,:28] @ [ld_b2;lo_b2]
        int j = i - 5370;
        float acc = m_b1[j];
#pragma unroll
        for (int o = 0; o < 7;  ++o) acc += m_w1[j*35 + o]     * ld_b2[o];
#pragma unroll
        for (int o = 0; o < 21; ++o) acc += m_w1[j*35 + 7 + o] * lo_b2[o];
        ws[OFF_BM + j] = acc;
    }
    else if (i < 5430) { int j = i - 5400; ws[OFF_BC + j] = c_b1[j]; }
    else if (i < 5437) { int k = i - 5430; ws[OFF_BOUT + k] = m_b2[k] + c_b2[k] + g_b2[k]; }
}

__global__ __launch_bounds__(NT, 3) void delan_main(
    const float* __restrict__ x, const float* __restrict__ ws, float* __restrict__ out)
{
    __shared__ float xs[NT * 21];
    const int t = threadIdx.x;
    const long long b0 = (long long)blockIdx.x * NT;

    // coalesced float4 stage of x into LDS
    {
        const float4* xb = (const float4*)(x + b0 * 21);
        float4* xs4 = (float4*)xs;
        for (int i = t; i < NT * 21 / 4; i += NT) xs4[i] = xb[i];
    }
    __syncthreads();

    const float* xt = &xs[t * 21];
    float q[7];
#pragma unroll
    for (int d = 0; d < 7; ++d) q[d] = xt[d];

    float acc_o[7];
#pragma unroll
    for (int k = 0; k < 7; ++k) acc_o[k] = ws[OFF_BOUT + k];

    // ---- g net: out += sin(q@g_w1^T + g_b1) @ g_w2^T ----
#pragma unroll 2
    for (int h = 0; h < 30; ++h) {
        float pre = ws[OFF_BG + h];
#pragma unroll
        for (int d = 0; d < 7; ++d) pre += q[d] * ws[OFF_W1G + h*8 + d];
        float s = __sinf(pre);
#pragma unroll
        for (int k = 0; k < 7; ++k) acc_o[k] += s * ws[OFF_G2T + h*8 + k];
    }

    // ---- m/c hidden pre-activations ----
    float mz[30], cz[30];
#pragma unroll
    for (int j = 0; j < 30; ++j) { mz[j] = ws[OFF_BM + j]; cz[j] = ws[OFF_BC + j]; }

#pragma unroll 1
    for (int d = 0; d < 7; ++d) {
        float qd  = xt[7 + d];
        float qdd = xt[14 + d];
#pragma unroll
        for (int j = 0; j < 30; ++j) {
            mz[j] += qdd * ws[OFF_MQT + d*32 + j];
            cz[j] += qd  * ws[OFF_CQT + d*32 + j];
        }
    }

    // ---- ld path: transcendental burst, then pure-FMA matvec ----
    {
        float s[30], c[30];
#pragma unroll
        for (int h = 0; h < 30; ++h) {
            float pre = ws[OFF_BLD + h];
#pragma unroll
            for (int d = 0; d < 7; ++d) pre += q[d] * ws[OFF_W1LD + h*8 + d];
            s[h] = __sinf(pre); c[h] = __cosf(pre);
        }
#pragma unroll 2
        for (int h = 0; h < 30; ++h) {
            const float* wr = &ws[OFF_LD + h*64];
#pragma unroll
            for (int j = 0; j < 30; ++j) {
                mz[j] += s[h] * wr[j];
                cz[j] += c[h] * wr[32 + j];
            }
        }
    }

    // ---- lo path ----
    {
        float s[30], c[30];
#pragma unroll
        for (int h = 0; h < 30; ++h) {
            float pre = ws[OFF_BLO + h];
#pragma unroll
            for (int d = 0; d < 7; ++d) pre += q[d] * ws[OFF_W1LO + h*8 + d];
            s[h] = __sinf(pre); c[h] = __cosf(pre);
        }
#pragma unroll 2
        for (int h = 0; h < 30; ++h) {
            const float* wr = &ws[OFF_LO + h*64];
#pragma unroll
            for (int j = 0; j < 30; ++j) {
                mz[j] += s[h] * wr[j];
                cz[j] += c[h] * wr[32 + j];
            }
        }
    }

    // ---- sigmoid + second layers of m/c nets ----
#pragma unroll 2
    for (int j = 0; j < 30; ++j) {
        float em = __expf(-mz[j]);
        float sm = __builtin_amdgcn_rcpf(1.f + em);
        float ec = __expf(-cz[j]);
        float sc = __builtin_amdgcn_rcpf(1.f + ec);
#pragma unroll
        for (int k = 0; k < 7; ++k)
            acc_o[k] += sm * ws[OFF_M2T + j*8 + k] + sc * ws[OFF_C2T + j*8 + k];
    }

    __syncthreads();
#pragma unroll
    for (int k = 0; k < 7; ++k) xs[t*7 + k] = acc_o[k];
    __syncthreads();
    {
        const float4* xs4 = (const float4*)xs;
        float4* ob = (float4*)(out + b0 * 7);
        for (int i = t; i < NT * 7 / 4; i += NT) ob[i] = xs4[i];
    }
}

extern "C" void kernel_launch(void* const* d_in, const int* in_sizes, int n_in,
                              void* d_out, int out_size, void* d_ws, size_t ws_size,
                              hipStream_t stream)
{
    const float* x = (const float*)d_in[0];
    float* ws = (float*)d_ws;

    precompute_kernel<<<(5437 + 63) / 64, 64, 0, stream>>>(
        (const float*)d_in[1],  (const float*)d_in[2],
        (const float*)d_in[3],  (const float*)d_in[4],
        (const float*)d_in[5],  (const float*)d_in[6],
        (const float*)d_in[7],  (const float*)d_in[8],
        (const float*)d_in[9],  (const float*)d_in[10],
        (const float*)d_in[11], (const float*)d_in[12],
        (const float*)d_in[13], (const float*)d_in[14],
        (const float*)d_in[15], (const float*)d_in[16],
        (const float*)d_in[17], (const float*)d_in[18],
        (const float*)d_in[19], (const float*)d_in[20],
        ws);

    const int batch = out_size / 7;            // 262144
    const int nblk  = batch / NT;              // 1024
    delan_main<<<nblk, NT, 0, stream>>>(x, ws, (float*)d_out);
}

// Round 4
// 133.870 us; speedup vs baseline: 1.3353x; 1.3353x over previous
//
#include <hip/hip_runtime.h>

// DeLaN sin-net fused kernel for MI355X (gfx950) — R3: full MFMA pipeline.
//
// Per wave, per 16-element tile (no __syncthreads anywhere; per-wave LDS bufs):
//   MFMA0: pre[16x16x2nc] = [q|1](bf16) @ [W1^T|b1](bf16)   for ld/lo/g   (6 mfma)
//   sincos (C-layout) -> per-wave LDS transpose -> A-frags
//   GEMM1: mz/cz[16x30] = [sin|sin|qdd,1] @ [PT;QT;MQT,BM]               (12 mfma)
//   sigmoid -> LDS -> GEMM2: out[16x7] = [sig|sig|sin_g] @ [m2;c2;g2]^T  (3 mfma)
// All 21 B-frags are loop-invariant registers; weight streaming eliminated.
// All A-side pad slots hit zeroed B-rows (precompute zeroes pads) -> no NaN.
// R2 lesson honored: no dynamically-indexed private arrays (all loops unrolled).

#define NT 256

typedef short bf16x8 __attribute__((ext_vector_type(8)));
typedef float f32x4  __attribute__((ext_vector_type(4)));

__device__ inline unsigned short f2b(float f) {
    union { float f; unsigned u; } v; v.f = f;
    return (unsigned short)((v.u + 0x7FFF + ((v.u >> 16) & 1)) >> 16);
}

// pack offsets in shorts, relative to ((ushort*)ws + 32); first 16 floats = BOUT
constexpr int PW_LD = 0;      // [nc][n][k] 2*512 : W1ld rows h=nc*16+n, k<7 w, k=7 b
constexpr int PW_LO = 1024;
constexpr int PW_G  = 2048;
constexpr int PB_MZ = 3072;   // [kc][nc][n][k] 3*1024 : kc0 PT, kc1 QT, kc2 MQT|BM
constexpr int PB_CZ = 6144;   //                        kc0 AT, kc1 BT, kc2 CQT|BC
constexpr int PB_O  = 9216;   // [kc][n][k] 3*512 : kc0 m_w2, kc1 c_w2, kc2 g_w2
constexpr int NPACK = 10752;

__global__ void precompute_kernel(
    const float* __restrict__ ld_w1, const float* __restrict__ ld_b1,
    const float* __restrict__ ld_w2, const float* __restrict__ ld_b2,
    const float* __restrict__ lo_w1, const float* __restrict__ lo_b1,
    const float* __restrict__ lo_w2, const float* __restrict__ lo_b2,
    const float* __restrict__ g_w1,  const float* __restrict__ g_b1,
    const float* __restrict__ g_w2,  const float* __restrict__ g_b2,
    const float* __restrict__ m_w1,  const float* __restrict__ m_b1,
    const float* __restrict__ m_w2,  const float* __restrict__ m_b2,
    const float* __restrict__ c_w1,  const float* __restrict__ c_b1,
    const float* __restrict__ c_w2,  const float* __restrict__ c_b2,
    float* __restrict__ ws)
{
    int i = blockIdx.x * blockDim.x + threadIdx.x;
    if (i < 16) { ws[i] = (i < 7) ? (m_b2[i] + c_b2[i] + g_b2[i]) : 0.f; return; }
    int r = i - 16;
    if (r >= NPACK) return;
    unsigned short* wp = (unsigned short*)ws + 32;
    float val = 0.f;
    if (r < 3072) {                                   // PW tables (W1 | b1)
        int tb = r / 1024, rr = r % 1024;
        int nc = rr >> 9, n = (rr >> 5) & 15, k = rr & 31, h = nc * 16 + n;
        const float* W1 = (tb == 0) ? ld_w1 : (tb == 1) ? lo_w1 : g_w1;
        const float* B1 = (tb == 0) ? ld_b1 : (tb == 1) ? lo_b1 : g_b1;
        if (h < 30) { if (k < 7) val = W1[h*7 + k]; else if (k == 7) val = B1[h]; }
    } else if (r < 6144) {                            // PB_MZ
        int rr = r - 3072; int kc = rr >> 10; rr &= 1023;
        int nc = rr >> 9, n = (rr >> 5) & 15, k = rr & 31, j = nc * 16 + n;
        if (j < 30) {
            if (kc == 0) {
                if (k < 30) { float a = 0.f;
                    for (int o = 0; o < 7; ++o) a += m_w1[j*35 + o] * ld_w2[o*30 + k];
                    val = a; }
            } else if (kc == 1) {
                if (k < 30) { float a = 0.f;
                    for (int o = 0; o < 21; ++o) a += m_w1[j*35 + 7 + o] * lo_w2[o*30 + k];
                    val = a; }
            } else {
                if (k < 7) val = m_w1[j*35 + 28 + k];
                else if (k == 7) { float a = m_b1[j];
                    for (int o = 0; o < 7;  ++o) a += m_w1[j*35 + o]     * ld_b2[o];
                    for (int o = 0; o < 21; ++o) a += m_w1[j*35 + 7 + o] * lo_b2[o];
                    val = a; }
            }
        }
    } else if (r < 9216) {                            // PB_CZ
        int rr = r - 6144; int kc = rr >> 10; rr &= 1023;
        int nc = rr >> 9, n = (rr >> 5) & 15, k = rr & 31, j = nc * 16 + n;
        if (j < 30) {
            if (kc == 0) {
                if (k < 30) { float a = 0.f;                 // AT[h=k][j]
                    for (int o = 0; o < 7; ++o) { float t = 0.f;
                        for (int d = 0; d < 7; ++d) t += c_w1[j*203 + o*7 + d] * ld_w1[k*7 + d];
                        a += ld_w2[o*30 + k] * t; }
                    val = a; }
            } else if (kc == 1) {
                if (k < 30) { float a = 0.f;                 // BT[h=k][j]
                    for (int o = 0; o < 21; ++o) { float t = 0.f;
                        for (int d = 0; d < 7; ++d) t += c_w1[j*203 + (7+o)*7 + d] * lo_w1[k*7 + d];
                        a += lo_w2[o*30 + k] * t; }
                    val = a; }
            } else {
                if (k < 7) val = c_w1[j*203 + 196 + k];
                else if (k == 7) val = c_b1[j];
            }
        }
    } else {                                          // PB_O
        int rr = r - 9216; int kc = rr >> 9, n = (rr >> 5) & 15, k = rr & 31;
        if (n < 7 && k < 30)
            val = ((kc == 0) ? m_w2 : (kc == 1) ? c_w2 : g_w2)[n*30 + k];
    }
    wp[r] = f2b(val);
}

#define MFMA(a, b, c) __builtin_amdgcn_mfma_f32_16x16x32_bf16((a), (b), (c), 0, 0, 0)

__global__ __launch_bounds__(NT, 3) void delan_main(
    const float* __restrict__ x, const float* __restrict__ ws, float* __restrict__ out)
{
    // per-wave LDS: sin[16][72], cos[16][72], sig[16][104] shorts (16B-aligned strides)
    __shared__ __align__(16) unsigned short L[4 * 3968];
    const int lane = threadIdx.x & 63, wid = threadIdx.x >> 6;
    const int n15 = lane & 15, quad = lane >> 4;
    unsigned short* Ls = L + wid * 3968;
    unsigned short* Lc = Ls + 1152;
    unsigned short* Lg = Ls + 2304;

    const unsigned short* wp = (const unsigned short*)ws + 32;
    const int fo = n15 * 32 + quad * 8;

    // ---- loop-invariant B-fragments (registers) ----
    bf16x8 bw_ld[2], bw_lo[2], bw_g[2], bm[3][2], bc[3][2], bo[3];
#pragma unroll
    for (int c = 0; c < 2; ++c) {
        bw_ld[c] = *(const bf16x8*)(wp + PW_LD + c*512 + fo);
        bw_lo[c] = *(const bf16x8*)(wp + PW_LO + c*512 + fo);
        bw_g[c]  = *(const bf16x8*)(wp + PW_G  + c*512 + fo);
#pragma unroll
        for (int kc = 0; kc < 3; ++kc) {
            bm[kc][c] = *(const bf16x8*)(wp + PB_MZ + kc*1024 + c*512 + fo);
            bc[kc][c] = *(const bf16x8*)(wp + PB_CZ + kc*1024 + c*512 + fo);
        }
    }
#pragma unroll
    for (int kc = 0; kc < 3; ++kc)
        bo[kc] = *(const bf16x8*)(wp + PB_O + kc*512 + fo);
    const float bout = ws[n15];        // 0 for n15 >= 7

    const f32x4 zero4 = {0.f, 0.f, 0.f, 0.f};

    for (int t = 0; t < 4; ++t) {
        const int eb = blockIdx.x * 256 + wid * 64 + t * 16;

        // x for element m = n15 (only quad-0 lanes feed A-fragments)
        float xq[21];
#pragma unroll
        for (int d = 0; d < 21; ++d) xq[d] = 0.f;
        if (quad == 0) {
            const float* xp = x + (size_t)(eb + n15) * 21;
#pragma unroll
            for (int d = 0; d < 21; ++d) xq[d] = xp[d];
        }

        // ---- MFMA0: pre-activations for ld / lo / g ----
        bf16x8 a0;
#pragma unroll
        for (int d = 0; d < 7; ++d) a0[d] = (short)f2b(xq[d]);
        a0[7] = (quad == 0) ? (short)0x3F80 : (short)0;     // bias-1 column

        f32x4 pld[2], plo[2], pg[2];
#pragma unroll
        for (int c = 0; c < 2; ++c) {
            pld[c] = MFMA(a0, bw_ld[c], zero4);
            plo[c] = MFMA(a0, bw_lo[c], zero4);
            pg[c]  = MFMA(a0, bw_g[c],  zero4);
        }

        // ---- sincos burst, C-layout -> LDS (rows m = quad*4+rg, col h = c*16+n15) ----
#pragma unroll
        for (int c = 0; c < 2; ++c) {
            const int h = c * 16 + n15;
#pragma unroll
            for (int rg = 0; rg < 4; ++rg) {
                const int m = quad * 4 + rg;
                float p1 = pld[c][rg];
                Ls[m*72 + h]      = f2b(__sinf(p1));
                Lc[m*72 + h]      = f2b(__cosf(p1));
                float p2 = plo[c][rg];
                Ls[m*72 + 32 + h] = f2b(__sinf(p2));
                Lc[m*72 + 32 + h] = f2b(__cosf(p2));
                Lg[m*104 + 64 + h] = f2b(__sinf(pg[c][rg]));
            }
        }

        // ---- GEMM1: mz, cz ----
        bf16x8 as0 = *(const bf16x8*)(Ls + n15*72 + quad*8);
        bf16x8 as1 = *(const bf16x8*)(Ls + n15*72 + 32 + quad*8);
        bf16x8 ac0 = *(const bf16x8*)(Lc + n15*72 + quad*8);
        bf16x8 ac1 = *(const bf16x8*)(Lc + n15*72 + 32 + quad*8);
        bf16x8 add_, aqd_;
#pragma unroll
        for (int d = 0; d < 7; ++d) { add_[d] = (short)f2b(xq[14 + d]); aqd_[d] = (short)f2b(xq[7 + d]); }
        add_[7] = a0[7]; aqd_[7] = a0[7];

        f32x4 mz[2], cz[2];
#pragma unroll
        for (int c = 0; c < 2; ++c) {
            f32x4 m_ = MFMA(as0, bm[0][c], zero4);
            m_ = MFMA(as1, bm[1][c], m_);
            mz[c] = MFMA(add_, bm[2][c], m_);
            f32x4 c_ = MFMA(ac0, bc[0][c], zero4);
            c_ = MFMA(ac1, bc[1][c], c_);
            cz[c] = MFMA(aqd_, bc[2][c], c_);
        }

        // ---- sigmoid -> LDS ----
#pragma unroll
        for (int c = 0; c < 2; ++c) {
            const int j = c * 16 + n15;
#pragma unroll
            for (int rg = 0; rg < 4; ++rg) {
                const int m = quad * 4 + rg;
                Lg[m*104 + j]      = f2b(__builtin_amdgcn_rcpf(1.f + __expf(-mz[c][rg])));
                Lg[m*104 + 32 + j] = f2b(__builtin_amdgcn_rcpf(1.f + __expf(-cz[c][rg])));
            }
        }

        // ---- GEMM2: out = [sig_m | sig_c | sin_g] @ [m2;c2;g2]^T ----
        bf16x8 ag0 = *(const bf16x8*)(Lg + n15*104 + quad*8);
        bf16x8 ag1 = *(const bf16x8*)(Lg + n15*104 + 32 + quad*8);
        bf16x8 ag2 = *(const bf16x8*)(Lg + n15*104 + 64 + quad*8);
        f32x4 o = MFMA(ag0, bo[0], zero4);
        o = MFMA(ag1, bo[1], o);
        o = MFMA(ag2, bo[2], o);

        if (n15 < 7) {
            float* op = out + (size_t)(eb + quad * 4) * 7 + n15;
            op[0]  = o[0] + bout;
            op[7]  = o[1] + bout;
            op[14] = o[2] + bout;
            op[21] = o[3] + bout;
        }
    }
}

extern "C" void kernel_launch(void* const* d_in, const int* in_sizes, int n_in,
                              void* d_out, int out_size, void* d_ws, size_t ws_size,
                              hipStream_t stream)
{
    const float* x = (const float*)d_in[0];
    float* ws = (float*)d_ws;

    precompute_kernel<<<(16 + NPACK + 255) / 256, 256, 0, stream>>>(
        (const float*)d_in[1],  (const float*)d_in[2],
        (const float*)d_in[3],  (const float*)d_in[4],
        (const float*)d_in[5],  (const float*)d_in[6],
        (const float*)d_in[7],  (const float*)d_in[8],
        (const float*)d_in[9],  (const float*)d_in[10],
        (const float*)d_in[11], (const float*)d_in[12],
        (const float*)d_in[13], (const float*)d_in[14],
        (const float*)d_in[15], (const float*)d_in[16],
        (const float*)d_in[17], (const float*)d_in[18],
        (const float*)d_in[19], (const float*)d_in[20],
        ws);

    const int batch = out_size / 7;            // 262144
    const int nblk  = batch / NT;              // 1024
    delan_main<<<nblk, NT, 0, stream>>>(x, ws, (float*)d_out);
}

// Round 6
// 132.967 us; speedup vs baseline: 1.3443x; 1.0068x over previous
//
#include <hip/hip_runtime.h>

// DeLaN sin-net fused kernel for MI355X (gfx950) — R5.
// = R3's proven per-wave MFMA pipeline (separate Ls/Lc/Lg buffers, sigmoid->Lg,
//   NO smem overlap, NO in-place overwrite — R4's two hazards reverted)
// + R4's x path win, made safe: per-thread bf16 pack of x into a DEDICATED LDS
//   record array [q|1][qd|1][qdd|1] (24 shorts); every MFMA A-fragment is one
//   unmasked ds_read_b128. Neighbor-spill reads (quad>=1) hit the next record
//   or the zeroed 64B tail, always multiplied by zeroed B-rows (k>=8).

#define NT 256

typedef short bf16x8 __attribute__((ext_vector_type(8)));
typedef float f32x4  __attribute__((ext_vector_type(4)));

__device__ inline unsigned short f2b(float f) {
    union { float f; unsigned u; } v; v.f = f;
    return (unsigned short)((v.u + 0x7FFF + ((v.u >> 16) & 1)) >> 16);
}
__device__ inline unsigned pk2(float lo, float hi) {
    return (unsigned)f2b(lo) | ((unsigned)f2b(hi) << 16);
}

// pack offsets in shorts, relative to ((ushort*)ws + 32); first 16 floats = BOUT
constexpr int PW_LD = 0;      // [nc][n][k] 2*512 : W1ld rows h=nc*16+n, k<7 w, k=7 b
constexpr int PW_LO = 1024;
constexpr int PW_G  = 2048;
constexpr int PB_MZ = 3072;   // [kc][nc][n][k] 3*1024 : kc0 PT, kc1 QT, kc2 MQT|BM
constexpr int PB_CZ = 6144;   //                        kc0 AT, kc1 BT, kc2 CQT|BC
constexpr int PB_O  = 9216;   // [kc][n][k] 3*512 : kc0 m_w2, kc1 c_w2, kc2 g_w2
constexpr int NPACK = 10752;

__global__ void precompute_kernel(
    const float* __restrict__ ld_w1, const float* __restrict__ ld_b1,
    const float* __restrict__ ld_w2, const float* __restrict__ ld_b2,
    const float* __restrict__ lo_w1, const float* __restrict__ lo_b1,
    const float* __restrict__ lo_w2, const float* __restrict__ lo_b2,
    const float* __restrict__ g_w1,  const float* __restrict__ g_b1,
    const float* __restrict__ g_w2,  const float* __restrict__ g_b2,
    const float* __restrict__ m_w1,  const float* __restrict__ m_b1,
    const float* __restrict__ m_w2,  const float* __restrict__ m_b2,
    const float* __restrict__ c_w1,  const float* __restrict__ c_b1,
    const float* __restrict__ c_w2,  const float* __restrict__ c_b2,
    float* __restrict__ ws)
{
    int i = blockIdx.x * blockDim.x + threadIdx.x;
    if (i < 16) { ws[i] = (i < 7) ? (m_b2[i] + c_b2[i] + g_b2[i]) : 0.f; return; }
    int r = i - 16;
    if (r >= NPACK) return;
    unsigned short* wp = (unsigned short*)ws + 32;
    float val = 0.f;
    if (r < 3072) {                                   // PW tables (W1 | b1)
        int tb = r / 1024, rr = r % 1024;
        int nc = rr >> 9, n = (rr >> 5) & 15, k = rr & 31, h = nc * 16 + n;
        const float* W1 = (tb == 0) ? ld_w1 : (tb == 1) ? lo_w1 : g_w1;
        const float* B1 = (tb == 0) ? ld_b1 : (tb == 1) ? lo_b1 : g_b1;
        if (h < 30) { if (k < 7) val = W1[h*7 + k]; else if (k == 7) val = B1[h]; }
    } else if (r < 6144) {                            // PB_MZ
        int rr = r - 3072; int kc = rr >> 10; rr &= 1023;
        int nc = rr >> 9, n = (rr >> 5) & 15, k = rr & 31, j = nc * 16 + n;
        if (j < 30) {
            if (kc == 0) {
                if (k < 30) { float a = 0.f;
                    for (int o = 0; o < 7; ++o) a += m_w1[j*35 + o] * ld_w2[o*30 + k];
                    val = a; }
            } else if (kc == 1) {
                if (k < 30) { float a = 0.f;
                    for (int o = 0; o < 21; ++o) a += m_w1[j*35 + 7 + o] * lo_w2[o*30 + k];
                    val = a; }
            } else {
                if (k < 7) val = m_w1[j*35 + 28 + k];
                else if (k == 7) { float a = m_b1[j];
                    for (int o = 0; o < 7;  ++o) a += m_w1[j*35 + o]     * ld_b2[o];
                    for (int o = 0; o < 21; ++o) a += m_w1[j*35 + 7 + o] * lo_b2[o];
                    val = a; }
            }
        }
    } else if (r < 9216) {                            // PB_CZ
        int rr = r - 6144; int kc = rr >> 10; rr &= 1023;
        int nc = rr >> 9, n = (rr >> 5) & 15, k = rr & 31, j = nc * 16 + n;
        if (j < 30) {
            if (kc == 0) {
                if (k < 30) { float a = 0.f;                 // AT[h=k][j]
                    for (int o = 0; o < 7; ++o) { float t = 0.f;
                        for (int d = 0; d < 7; ++d) t += c_w1[j*203 + o*7 + d] * ld_w1[k*7 + d];
                        a += ld_w2[o*30 + k] * t; }
                    val = a; }
            } else if (kc == 1) {
                if (k < 30) { float a = 0.f;                 // BT[h=k][j]
                    for (int o = 0; o < 21; ++o) { float t = 0.f;
                        for (int d = 0; d < 7; ++d) t += c_w1[j*203 + (7+o)*7 + d] * lo_w1[k*7 + d];
                        a += lo_w2[o*30 + k] * t; }
                    val = a; }
            } else {
                if (k < 7) val = c_w1[j*203 + 196 + k];
                else if (k == 7) val = c_b1[j];
            }
        }
    } else {                                          // PB_O
        int rr = r - 9216; int kc = rr >> 9, n = (rr >> 5) & 15, k = rr & 31;
        if (n < 7 && k < 30)
            val = ((kc == 0) ? m_w2 : (kc == 1) ? c_w2 : g_w2)[n*30 + k];
    }
    wp[r] = f2b(val);
}

#define MFMA(a, b, c) __builtin_amdgcn_mfma_f32_16x16x32_bf16((a), (b), (c), 0, 0, 0)

__global__ __launch_bounds__(NT, 3) void delan_main(
    const float* __restrict__ x, const float* __restrict__ ws, float* __restrict__ out)
{
    // DEDICATED regions, no overlap (R3 discipline):
    __shared__ __align__(16) unsigned short xs2[NT * 24 + 32];   // 12352 B
    __shared__ __align__(16) unsigned short Lbuf[4 * 3968];      // 31744 B

    const int tid = threadIdx.x;
    const int lane = tid & 63, wid = tid >> 6;
    const int n15 = lane & 15, quad = lane >> 4;

    // ---- per-thread bf16 pack of one element: [q|1][qd|1][qdd|1], 24 shorts ----
    {
        const float* xp = x + (size_t)(blockIdx.x * NT + tid) * 21;
        float v[21];
#pragma unroll
        for (int d = 0; d < 21; ++d) v[d] = xp[d];
        int4* dst = (int4*)(xs2 + tid * 24);
#pragma unroll
        for (int g = 0; g < 3; ++g) {
            int4 u;
            u.x = (int)pk2(v[g*7 + 0], v[g*7 + 1]);
            u.y = (int)pk2(v[g*7 + 2], v[g*7 + 3]);
            u.z = (int)pk2(v[g*7 + 4], v[g*7 + 5]);
            u.w = (int)pk2(v[g*7 + 6], 1.0f);
            dst[g] = u;
        }
    }
    if (tid < 16) ((unsigned*)(xs2 + NT * 24))[tid] = 0;   // zero 64B tail pad
    __syncthreads();

    // per-wave transpose buffers (R3 layout: sin | cos | sig+sin_g)
    unsigned short* Ls = Lbuf + wid * 3968;     // [16][72]  sin_ld | sin_lo
    unsigned short* Lc = Ls + 1152;             // [16][72]  cos_ld | cos_lo
    unsigned short* Lg = Ls + 2304;             // [16][104] sig_m | sig_c | sin_g

    const unsigned short* wp = (const unsigned short*)ws + 32;
    const int fo = n15 * 32 + quad * 8;

    // ---- loop-invariant B-fragments (registers) ----
    bf16x8 bw_ld[2], bw_lo[2], bw_g[2], bm[3][2], bc[3][2], bo[3];
#pragma unroll
    for (int c = 0; c < 2; ++c) {
        bw_ld[c] = *(const bf16x8*)(wp + PW_LD + c*512 + fo);
        bw_lo[c] = *(const bf16x8*)(wp + PW_LO + c*512 + fo);
        bw_g[c]  = *(const bf16x8*)(wp + PW_G  + c*512 + fo);
#pragma unroll
        for (int kc = 0; kc < 3; ++kc) {
            bm[kc][c] = *(const bf16x8*)(wp + PB_MZ + kc*1024 + c*512 + fo);
            bc[kc][c] = *(const bf16x8*)(wp + PB_CZ + kc*1024 + c*512 + fo);
        }
    }
#pragma unroll
    for (int kc = 0; kc < 3; ++kc)
        bo[kc] = *(const bf16x8*)(wp + PB_O + kc*512 + fo);
    const float bout = ws[n15];        // 0 for n15 >= 7

    const f32x4 zero4 = {0.f, 0.f, 0.f, 0.f};

#pragma unroll 1
    for (int t = 0; t < 4; ++t) {
        const int elb = wid * 64 + t * 16;                // element base in block
        const unsigned short* ep = xs2 + (elb + n15) * 24;

        // ---- A-fragments: one ds_read_b128 each, all 64 lanes ----
        bf16x8 a0  = *(const bf16x8*)(ep + quad * 8);          // [q|1]
        bf16x8 aqd = *(const bf16x8*)(ep + 8 + quad * 8);      // [qDot|1]
        bf16x8 add = *(const bf16x8*)(ep + 16 + quad * 8);     // [qDDot|1]

        // ---- MFMA0: pre-activations for ld / lo / g ----
        f32x4 pld[2], plo[2], pg[2];
#pragma unroll
        for (int c = 0; c < 2; ++c) {
            pld[c] = MFMA(a0, bw_ld[c], zero4);
            plo[c] = MFMA(a0, bw_lo[c], zero4);
            pg[c]  = MFMA(a0, bw_g[c],  zero4);
        }

        // ---- sincos burst -> LDS transpose (writes cover cols 0..31 incl pads) ----
#pragma unroll
        for (int c = 0; c < 2; ++c) {
            const int h = c * 16 + n15;
#pragma unroll
            for (int rg = 0; rg < 4; ++rg) {
                const int m = quad * 4 + rg;
                float p1 = pld[c][rg];
                Ls[m*72 + h]       = f2b(__sinf(p1));
                Lc[m*72 + h]       = f2b(__cosf(p1));
                float p2 = plo[c][rg];
                Ls[m*72 + 32 + h]  = f2b(__sinf(p2));
                Lc[m*72 + 32 + h]  = f2b(__cosf(p2));
                Lg[m*104 + 64 + h] = f2b(__sinf(pg[c][rg]));
            }
        }

        // ---- GEMM1: mz, cz ----
        bf16x8 as0 = *(const bf16x8*)(Ls + n15*72 + quad*8);
        bf16x8 as1 = *(const bf16x8*)(Ls + n15*72 + 32 + quad*8);
        bf16x8 ac0 = *(const bf16x8*)(Lc + n15*72 + quad*8);
        bf16x8 ac1 = *(const bf16x8*)(Lc + n15*72 + 32 + quad*8);

        f32x4 mz[2], cz[2];
#pragma unroll
        for (int c = 0; c < 2; ++c) {
            f32x4 m_ = MFMA(as0, bm[0][c], zero4);
            m_ = MFMA(as1, bm[1][c], m_);
            mz[c] = MFMA(add, bm[2][c], m_);
            f32x4 c_ = MFMA(ac0, bc[0][c], zero4);
            c_ = MFMA(ac1, bc[1][c], c_);
            cz[c] = MFMA(aqd, bc[2][c], c_);
        }

        // ---- sigmoid -> Lg (separate buffer, R3 discipline) ----
#pragma unroll
        for (int c = 0; c < 2; ++c) {
            const int j = c * 16 + n15;
#pragma unroll
            for (int rg = 0; rg < 4; ++rg) {
                const int m = quad * 4 + rg;
                Lg[m*104 + j]      = f2b(__builtin_amdgcn_rcpf(1.f + __expf(-mz[c][rg])));
                Lg[m*104 + 32 + j] = f2b(__builtin_amdgcn_rcpf(1.f + __expf(-cz[c][rg])));
            }
        }

        // ---- GEMM2: out = [sig_m | sig_c | sin_g] @ [m2;c2;g2]^T ----
        bf16x8 ag0 = *(const bf16x8*)(Lg + n15*104 + quad*8);
        bf16x8 ag1 = *(const bf16x8*)(Lg + n15*104 + 32 + quad*8);
        bf16x8 ag2 = *(const bf16x8*)(Lg + n15*104 + 64 + quad*8);
        f32x4 o = MFMA(ag0, bo[0], zero4);
        o = MFMA(ag1, bo[1], o);
        o = MFMA(ag2, bo[2], o);

        if (n15 < 7) {
            const int eb = blockIdx.x * NT + elb;
            float* op = out + (size_t)(eb + quad * 4) * 7 + n15;
            op[0]  = o[0] + bout;
            op[7]  = o[1] + bout;
            op[14] = o[2] + bout;
            op[21] = o[3] + bout;
        }
    }
}

extern "C" void kernel_launch(void* const* d_in, const int* in_sizes, int n_in,
                              void* d_out, int out_size, void* d_ws, size_t ws_size,
                              hipStream_t stream)
{
    const float* x = (const float*)d_in[0];
    float* ws = (float*)d_ws;

    precompute_kernel<<<(16 + NPACK + 255) / 256, 256, 0, stream>>>(
        (const float*)d_in[1],  (const float*)d_in[2],
        (const float*)d_in[3],  (const float*)d_in[4],
        (const float*)d_in[5],  (const float*)d_in[6],
        (const float*)d_in[7],  (const float*)d_in[8],
        (const float*)d_in[9],  (const float*)d_in[10],
        (const float*)d_in[11], (const float*)d_in[12],
        (const float*)d_in[13], (const float*)d_in[14],
        (const float*)d_in[15], (const float*)d_in[16],
        (const float*)d_in[17], (const float*)d_in[18],
        (const float*)d_in[19], (const float*)d_in[20],
        ws);

    const int batch = out_size / 7;            // 262144
    const int nblk  = batch / NT;              // 1024
    delan_main<<<nblk, NT, 0, stream>>>(x, ws, (float*)d_out);
}

// Round 7
// 132.068 us; speedup vs baseline: 1.3535x; 1.0068x over previous
//
#include <hip/hip_runtime.h>

// DeLaN sin-net fused kernel for MI355X (gfx950) — R6.
// = R5 (proven correct) + software-pipelined tile loop:
//   tile t+1's a0 ds_read + MFMA0 issue inside tile t's sincos-write ->
//   GEMM1-read lgkm turnaround. Pre-activations single-buffer staged (24 VGPR);
//   aqd/add re-read from xs2 at GEMM1 (no staging). Full unroll, constant
//   indices only (R2 scratch lesson). No LDS aliasing/overwrite (R4 lesson).
//   sin/cos share one range-reduction multiply via raw v_sin/v_cos builtins.

#define NT 256

typedef short bf16x8 __attribute__((ext_vector_type(8)));
typedef float f32x4  __attribute__((ext_vector_type(4)));

__device__ inline unsigned short f2b(float f) {
    union { float f; unsigned u; } v; v.f = f;
    return (unsigned short)((v.u + 0x7FFF + ((v.u >> 16) & 1)) >> 16);
}
__device__ inline unsigned pk2(float lo, float hi) {
    return (unsigned)f2b(lo) | ((unsigned)f2b(hi) << 16);
}

#define INV2PI 0.15915494309189535f

// pack offsets in shorts, relative to ((ushort*)ws + 32); first 16 floats = BOUT
constexpr int PW_LD = 0;      // [nc][n][k] 2*512 : W1ld rows h=nc*16+n, k<7 w, k=7 b
constexpr int PW_LO = 1024;
constexpr int PW_G  = 2048;
constexpr int PB_MZ = 3072;   // [kc][nc][n][k] 3*1024 : kc0 PT, kc1 QT, kc2 MQT|BM
constexpr int PB_CZ = 6144;   //                        kc0 AT, kc1 BT, kc2 CQT|BC
constexpr int PB_O  = 9216;   // [kc][n][k] 3*512 : kc0 m_w2, kc1 c_w2, kc2 g_w2
constexpr int NPACK = 10752;

__global__ void precompute_kernel(
    const float* __restrict__ ld_w1, const float* __restrict__ ld_b1,
    const float* __restrict__ ld_w2, const float* __restrict__ ld_b2,
    const float* __restrict__ lo_w1, const float* __restrict__ lo_b1,
    const float* __restrict__ lo_w2, const float* __restrict__ lo_b2,
    const float* __restrict__ g_w1,  const float* __restrict__ g_b1,
    const float* __restrict__ g_w2,  const float* __restrict__ g_b2,
    const float* __restrict__ m_w1,  const float* __restrict__ m_b1,
    const float* __restrict__ m_w2,  const float* __restrict__ m_b2,
    const float* __restrict__ c_w1,  const float* __restrict__ c_b1,
    const float* __restrict__ c_w2,  const float* __restrict__ c_b2,
    float* __restrict__ ws)
{
    int i = blockIdx.x * blockDim.x + threadIdx.x;
    if (i < 16) { ws[i] = (i < 7) ? (m_b2[i] + c_b2[i] + g_b2[i]) : 0.f; return; }
    int r = i - 16;
    if (r >= NPACK) return;
    unsigned short* wp = (unsigned short*)ws + 32;
    float val = 0.f;
    if (r < 3072) {                                   // PW tables (W1 | b1)
        int tb = r / 1024, rr = r % 1024;
        int nc = rr >> 9, n = (rr >> 5) & 15, k = rr & 31, h = nc * 16 + n;
        const float* W1 = (tb == 0) ? ld_w1 : (tb == 1) ? lo_w1 : g_w1;
        const float* B1 = (tb == 0) ? ld_b1 : (tb == 1) ? lo_b1 : g_b1;
        if (h < 30) { if (k < 7) val = W1[h*7 + k]; else if (k == 7) val = B1[h]; }
    } else if (r < 6144) {                            // PB_MZ
        int rr = r - 3072; int kc = rr >> 10; rr &= 1023;
        int nc = rr >> 9, n = (rr >> 5) & 15, k = rr & 31, j = nc * 16 + n;
        if (j < 30) {
            if (kc == 0) {
                if (k < 30) { float a = 0.f;
                    for (int o = 0; o < 7; ++o) a += m_w1[j*35 + o] * ld_w2[o*30 + k];
                    val = a; }
            } else if (kc == 1) {
                if (k < 30) { float a = 0.f;
                    for (int o = 0; o < 21; ++o) a += m_w1[j*35 + 7 + o] * lo_w2[o*30 + k];
                    val = a; }
            } else {
                if (k < 7) val = m_w1[j*35 + 28 + k];
                else if (k == 7) { float a = m_b1[j];
                    for (int o = 0; o < 7;  ++o) a += m_w1[j*35 + o]     * ld_b2[o];
                    for (int o = 0; o < 21; ++o) a += m_w1[j*35 + 7 + o] * lo_b2[o];
                    val = a; }
            }
        }
    } else if (r < 9216) {                            // PB_CZ
        int rr = r - 6144; int kc = rr >> 10; rr &= 1023;
        int nc = rr >> 9, n = (rr >> 5) & 15, k = rr & 31, j = nc * 16 + n;
        if (j < 30) {
            if (kc == 0) {
                if (k < 30) { float a = 0.f;                 // AT[h=k][j]
                    for (int o = 0; o < 7; ++o) { float t = 0.f;
                        for (int d = 0; d < 7; ++d) t += c_w1[j*203 + o*7 + d] * ld_w1[k*7 + d];
                        a += ld_w2[o*30 + k] * t; }
                    val = a; }
            } else if (kc == 1) {
                if (k < 30) { float a = 0.f;                 // BT[h=k][j]
                    for (int o = 0; o < 21; ++o) { float t = 0.f;
                        for (int d = 0; d < 7; ++d) t += c_w1[j*203 + (7+o)*7 + d] * lo_w1[k*7 + d];
                        a += lo_w2[o*30 + k] * t; }
                    val = a; }
            } else {
                if (k < 7) val = c_w1[j*203 + 196 + k];
                else if (k == 7) val = c_b1[j];
            }
        }
    } else {                                          // PB_O
        int rr = r - 9216; int kc = rr >> 9, n = (rr >> 5) & 15, k = rr & 31;
        if (n < 7 && k < 30)
            val = ((kc == 0) ? m_w2 : (kc == 1) ? c_w2 : g_w2)[n*30 + k];
    }
    wp[r] = f2b(val);
}

#define MFMA(a, b, c) __builtin_amdgcn_mfma_f32_16x16x32_bf16((a), (b), (c), 0, 0, 0)

__global__ __launch_bounds__(NT, 3) void delan_main(
    const float* __restrict__ x, const float* __restrict__ ws, float* __restrict__ out)
{
    // DEDICATED regions, no overlap:
    __shared__ __align__(16) unsigned short xs2[NT * 24 + 32];   // 12352 B
    __shared__ __align__(16) unsigned short Lbuf[4 * 3968];      // 31744 B

    const int tid = threadIdx.x;
    const int lane = tid & 63, wid = tid >> 6;
    const int n15 = lane & 15, quad = lane >> 4;

    // ---- per-thread bf16 pack of one element: [q|1][qd|1][qdd|1], 24 shorts ----
    {
        const float* xp = x + (size_t)(blockIdx.x * NT + tid) * 21;
        float v[21];
#pragma unroll
        for (int d = 0; d < 21; ++d) v[d] = xp[d];
        int4* dst = (int4*)(xs2 + tid * 24);
#pragma unroll
        for (int g = 0; g < 3; ++g) {
            int4 u;
            u.x = (int)pk2(v[g*7 + 0], v[g*7 + 1]);
            u.y = (int)pk2(v[g*7 + 2], v[g*7 + 3]);
            u.z = (int)pk2(v[g*7 + 4], v[g*7 + 5]);
            u.w = (int)pk2(v[g*7 + 6], 1.0f);
            dst[g] = u;
        }
    }
    if (tid < 16) ((unsigned*)(xs2 + NT * 24))[tid] = 0;   // zero 64B tail pad
    __syncthreads();

    // per-wave transpose buffers (sin | cos | sig+sin_g)
    unsigned short* Ls = Lbuf + wid * 3968;     // [16][72]  sin_ld | sin_lo
    unsigned short* Lc = Ls + 1152;             // [16][72]  cos_ld | cos_lo
    unsigned short* Lg = Ls + 2304;             // [16][104] sig_m | sig_c | sin_g

    const unsigned short* wp = (const unsigned short*)ws + 32;
    const int fo = n15 * 32 + quad * 8;

    // ---- loop-invariant B-fragments (registers) ----
    bf16x8 bw_ld[2], bw_lo[2], bw_g[2], bm[3][2], bc[3][2], bo[3];
#pragma unroll
    for (int c = 0; c < 2; ++c) {
        bw_ld[c] = *(const bf16x8*)(wp + PW_LD + c*512 + fo);
        bw_lo[c] = *(const bf16x8*)(wp + PW_LO + c*512 + fo);
        bw_g[c]  = *(const bf16x8*)(wp + PW_G  + c*512 + fo);
#pragma unroll
        for (int kc = 0; kc < 3; ++kc) {
            bm[kc][c] = *(const bf16x8*)(wp + PB_MZ + kc*1024 + c*512 + fo);
            bc[kc][c] = *(const bf16x8*)(wp + PB_CZ + kc*1024 + c*512 + fo);
        }
    }
#pragma unroll
    for (int kc = 0; kc < 3; ++kc)
        bo[kc] = *(const bf16x8*)(wp + PB_O + kc*512 + fo);
    const float bout = ws[n15];        // 0 for n15 >= 7

    const f32x4 zero4 = {0.f, 0.f, 0.f, 0.f};

    // ---- staged pre-activations (single-buffered; WAR resolved at VALU issue) ----
    f32x4 pld[2], plo[2], pg[2];

    // prologue: MFMA0 for tile 0
    {
        const unsigned short* ep0 = xs2 + (wid * 64 + n15) * 24;
        bf16x8 a0 = *(const bf16x8*)(ep0 + quad * 8);
#pragma unroll
        for (int c = 0; c < 2; ++c) {
            pld[c] = MFMA(a0, bw_ld[c], zero4);
            plo[c] = MFMA(a0, bw_lo[c], zero4);
            pg[c]  = MFMA(a0, bw_g[c],  zero4);
        }
    }

#pragma unroll
    for (int t = 0; t < 4; ++t) {
        const int elb = wid * 64 + t * 16;                // element base in block
        const unsigned short* ep = xs2 + (elb + n15) * 24;

        // ---- 1. sincos(t) from staged pre -> LDS transpose ----
#pragma unroll
        for (int c = 0; c < 2; ++c) {
            const int h = c * 16 + n15;
#pragma unroll
            for (int rg = 0; rg < 4; ++rg) {
                const int m = quad * 4 + rg;
                float r1 = pld[c][rg] * INV2PI;
                Ls[m*72 + h]       = f2b(__builtin_amdgcn_sinf(r1));
                Lc[m*72 + h]       = f2b(__builtin_amdgcn_cosf(r1));
                float r2 = plo[c][rg] * INV2PI;
                Ls[m*72 + 32 + h]  = f2b(__builtin_amdgcn_sinf(r2));
                Lc[m*72 + 32 + h]  = f2b(__builtin_amdgcn_cosf(r2));
                Lg[m*104 + 64 + h] = f2b(__builtin_amdgcn_sinf(pg[c][rg] * INV2PI));
            }
        }

        // ---- 2. prefetch tile t+1: a0 read + MFMA0 (fills the lgkm turnaround) ----
        if (t < 3) {
            const unsigned short* epn = xs2 + (elb + 16 + n15) * 24;
            bf16x8 a0n = *(const bf16x8*)(epn + quad * 8);
#pragma unroll
            for (int c = 0; c < 2; ++c) {
                pld[c] = MFMA(a0n, bw_ld[c], zero4);
                plo[c] = MFMA(a0n, bw_lo[c], zero4);
                pg[c]  = MFMA(a0n, bw_g[c],  zero4);
            }
        }

        // ---- 3. GEMM1(t): mz, cz ----
        bf16x8 as0 = *(const bf16x8*)(Ls + n15*72 + quad*8);
        bf16x8 as1 = *(const bf16x8*)(Ls + n15*72 + 32 + quad*8);
        bf16x8 ac0 = *(const bf16x8*)(Lc + n15*72 + quad*8);
        bf16x8 ac1 = *(const bf16x8*)(Lc + n15*72 + 32 + quad*8);
        bf16x8 aqd = *(const bf16x8*)(ep + 8 + quad * 8);      // [qDot|1]
        bf16x8 add = *(const bf16x8*)(ep + 16 + quad * 8);     // [qDDot|1]

        f32x4 mz[2], cz[2];
#pragma unroll
        for (int c = 0; c < 2; ++c) {
            f32x4 m_ = MFMA(as0, bm[0][c], zero4);
            m_ = MFMA(as1, bm[1][c], m_);
            mz[c] = MFMA(add, bm[2][c], m_);
            f32x4 c_ = MFMA(ac0, bc[0][c], zero4);
            c_ = MFMA(ac1, bc[1][c], c_);
            cz[c] = MFMA(aqd, bc[2][c], c_);
        }

        // ---- 4. sigmoid -> Lg ----
#pragma unroll
        for (int c = 0; c < 2; ++c) {
            const int j = c * 16 + n15;
#pragma unroll
            for (int rg = 0; rg < 4; ++rg) {
                const int m = quad * 4 + rg;
                Lg[m*104 + j]      = f2b(__builtin_amdgcn_rcpf(1.f + __expf(-mz[c][rg])));
                Lg[m*104 + 32 + j] = f2b(__builtin_amdgcn_rcpf(1.f + __expf(-cz[c][rg])));
            }
        }

        // ---- 5. GEMM2 + store ----
        bf16x8 ag0 = *(const bf16x8*)(Lg + n15*104 + quad*8);
        bf16x8 ag1 = *(const bf16x8*)(Lg + n15*104 + 32 + quad*8);
        bf16x8 ag2 = *(const bf16x8*)(Lg + n15*104 + 64 + quad*8);
        f32x4 o = MFMA(ag0, bo[0], zero4);
        o = MFMA(ag1, bo[1], o);
        o = MFMA(ag2, bo[2], o);

        if (n15 < 7) {
            const int eb = blockIdx.x * NT + elb;
            float* op = out + (size_t)(eb + quad * 4) * 7 + n15;
            op[0]  = o[0] + bout;
            op[7]  = o[1] + bout;
            op[14] = o[2] + bout;
            op[21] = o[3] + bout;
        }
    }
}

extern "C" void kernel_launch(void* const* d_in, const int* in_sizes, int n_in,
                              void* d_out, int out_size, void* d_ws, size_t ws_size,
                              hipStream_t stream)
{
    const float* x = (const float*)d_in[0];
    float* ws = (float*)d_ws;

    precompute_kernel<<<(16 + NPACK + 255) / 256, 256, 0, stream>>>(
        (const float*)d_in[1],  (const float*)d_in[2],
        (const float*)d_in[3],  (const float*)d_in[4],
        (const float*)d_in[5],  (const float*)d_in[6],
        (const float*)d_in[7],  (const float*)d_in[8],
        (const float*)d_in[9],  (const float*)d_in[10],
        (const float*)d_in[11], (const float*)d_in[12],
        (const float*)d_in[13], (const float*)d_in[14],
        (const float*)d_in[15], (const float*)d_in[16],
        (const float*)d_in[17], (const float*)d_in[18],
        (const float*)d_in[19], (const float*)d_in[20],
        ws);

    const int batch = out_size / 7;            // 262144
    const int nblk  = batch / NT;              // 1024
    delan_main<<<nblk, NT, 0, stream>>>(x, ws, (float*)d_out);
}